// Round 7
// baseline (1743.659 us; speedup 1.0000x reference)
//
#include <hip/hip_runtime.h>

// ---------- types ----------
typedef short short8 __attribute__((ext_vector_type(8)));   // 8 bf16 as i16
typedef float f32x4 __attribute__((ext_vector_type(4)));

#define GLOBAL_AS __attribute__((address_space(1)))
#define LDS_AS    __attribute__((address_space(3)))

__device__ __forceinline__ unsigned short f2bf(float f) {
    unsigned u = __builtin_bit_cast(unsigned, f);
    u += 0x7fffu + ((u >> 16) & 1u);          // round-to-nearest-even
    return (unsigned short)(u >> 16);
}

// ---------- convert kernels (memory-bound, vectorized) ----------
__global__ __launch_bounds__(256) void k_idx2bf(const int* __restrict__ idx,
                                                const float* __restrict__ cb,
                                                ushort* __restrict__ out, int n4) {
    int i = blockIdx.x * 256 + threadIdx.x;
    if (i >= n4) return;
    int4 v = reinterpret_cast<const int4*>(idx)[i];
    ushort4 o;
    o.x = f2bf(cb[v.x]); o.y = f2bf(cb[v.y]);
    o.z = f2bf(cb[v.z]); o.w = f2bf(cb[v.w]);
    reinterpret_cast<ushort4*>(out)[i] = o;
}

__global__ __launch_bounds__(256) void k_f2bf(const float* __restrict__ in,
                                              ushort* __restrict__ out, int n4) {
    int i = blockIdx.x * 256 + threadIdx.x;
    if (i >= n4) return;
    float4 v = reinterpret_cast<const float4*>(in)[i];
    ushort4 o;
    o.x = f2bf(v.x); o.y = f2bf(v.y); o.z = f2bf(v.z); o.w = f2bf(v.w);
    reinterpret_cast<ushort4*>(out)[i] = o;
}

// ---------- 256x256 read-ahead pipelined bf16 gemm_bt: C = A*B^T ----------
// 512 thr = 8 waves (2M x 4N), per-wave 128x64 out, BK=64, 2 K-tile LDS dbuf.
// SOFTWARE-PIPELINED READS: phase p issues the ds_reads for phase p+1's MFMA
// (double operand reg sets a0f/a1f, b0f/b1f), then barrier ->
// lgkmcnt(N = reads issued THIS phase) -> 16 MFMA. So each phase's operands
// were loaded one phase earlier; LDS service hides under the prior MFMA.
// Reads/tile: ph1=B1[4] ph2=A1[8] ph3=0 ph4=A0,B0(next)[12]; lgkm 4/8/0/12.
// Stages/tile t: ph1 AL(t+1)->other buf; ph2 AE(t+2), ph3 BE(t+2),
// ph4 BL(t+2) -> current buf. vmcnt fences at PHASE END (before end-barrier,
// so a barrier separates fence from dependent cross-wave reads): steady
// vmcnt(8) at ends of ph1 (completes AL(t)), ph3 (AE,BE(t+1)), ph4 (BL(t+1));
// each fenced load issued >=4 phases earlier -> never stalls. Region-reuse
// safety: every staged region's last ds_reads are drained by a counted lgkm
// >=1 barrier before the stage issues (checked per region).
// Swizzle (0 conflicts, r3-verified): linear LDS dest + pre-swizzled global
// col (slot s of row r holds s^(r&7)) + XOR'd ds_read address.

#define CH_AE(j) ((((j) & 8) << 1) | ((j) & 7))
#define CH_AL(j) (CH_AE(j) + 8)
#define CH_BE(j) ((((j) & 12) << 1) | ((j) & 3))
#define CH_BL(j) (CH_BE(j) + 4)

#define STAGE2(G, LDSBASE, KB, CF) do {                                         \
    const int c0_ = CF(2 * w);                                                  \
    const int c1_ = CF(2 * w + 1);                                              \
    __builtin_amdgcn_global_load_lds(                                           \
        (const GLOBAL_AS void*)((G) + (size_t)(c0_ * 8 + srow8) * 4096 + (KB) + scol), \
        (LDS_AS void*)((LDSBASE) + c0_ * 512), 16, 0, 0);                       \
    __builtin_amdgcn_global_load_lds(                                           \
        (const GLOBAL_AS void*)((G) + (size_t)(c1_ * 8 + srow8) * 4096 + (KB) + scol), \
        (LDS_AS void*)((LDSBASE) + c1_ * 512), 16, 0, 0);                       \
} while (0)

#define READ_A(DST, BASE, MH) do {                                              \
    _Pragma("unroll")                                                           \
    for (int k2 = 0; k2 < 2; ++k2)                                              \
        _Pragma("unroll")                                                       \
        for (int mi = 0; mi < 4; ++mi) {                                        \
            const int lb = (arow + (MH) * 64 + mi * 16) * 128 + k2 * 64 + fkb;  \
            DST[k2][mi] = *reinterpret_cast<const short8*>((const char*)(BASE) + (lb ^ swb)); \
        }                                                                       \
} while (0)

#define READ_B(DST, BASE, NH) do {                                              \
    _Pragma("unroll")                                                           \
    for (int k2 = 0; k2 < 2; ++k2)                                              \
        _Pragma("unroll")                                                       \
        for (int ni = 0; ni < 2; ++ni) {                                        \
            const int lb = (brow + (NH) * 32 + ni * 16) * 128 + k2 * 64 + fkb;  \
            DST[k2][ni] = *reinterpret_cast<const short8*>((const char*)(BASE) + (lb ^ swb)); \
        }                                                                       \
} while (0)

#define MFMA16(MH, NH, AF, BF)                                                  \
    _Pragma("unroll")                                                           \
    for (int k2 = 0; k2 < 2; ++k2)                                              \
        _Pragma("unroll")                                                       \
        for (int mi = 0; mi < 4; ++mi)                                          \
            _Pragma("unroll")                                                   \
            for (int ni = 0; ni < 2; ++ni)                                      \
                acc[(MH) * 4 + mi][(NH) * 2 + ni] =                             \
                    __builtin_amdgcn_mfma_f32_16x16x32_bf16(                    \
                        AF[k2][mi], BF[k2][ni], acc[(MH) * 4 + mi][(NH) * 2 + ni], 0, 0, 0)

#define VM(N) asm volatile("s_waitcnt vmcnt(" #N ")" ::: "memory")

#define ENDBAR do {                                                             \
    asm volatile("" ::: "memory");                                              \
    __builtin_amdgcn_s_barrier();                                               \
    asm volatile("" ::: "memory");                                              \
} while (0)

#define PHTOP do {                                                              \
    asm volatile("" ::: "memory");                                              \
    __builtin_amdgcn_s_barrier();                                               \
} while (0)

#define PHMID(N) do {                                                           \
    asm volatile("s_waitcnt lgkmcnt(" #N ")" ::: "memory");                     \
    __builtin_amdgcn_sched_barrier(0);                                          \
    __builtin_amdgcn_s_setprio(1);                                              \
} while (0)

// phase macros: reads-for-NEXT-phase + stage (__VA_ARGS__), barrier,
// counted lgkm, MFMA for THIS phase (operands read last phase)
#define PH1Q(Bt, ...) do { READ_B(b1f, Bt, 1); __VA_ARGS__;                     \
    PHTOP; PHMID(4);  MFMA16(0, 0, a0f, b0f);                                   \
    __builtin_amdgcn_s_setprio(0); } while (0)

#define PH2Q(At, ...) do { READ_A(a1f, At, 1); __VA_ARGS__;                     \
    PHTOP; PHMID(8);  MFMA16(0, 1, a0f, b1f);                                   \
    __builtin_amdgcn_s_setprio(0); } while (0)

#define PH3Q(...) do { __VA_ARGS__;                                             \
    PHTOP; PHMID(0);  MFMA16(1, 0, a1f, b0f);                                   \
    __builtin_amdgcn_s_setprio(0); } while (0)

#define PH4Q(An2, Bn2, ...) do { READ_A(a0f, An2, 0); READ_B(b0f, Bn2, 0);      \
    __VA_ARGS__;                                                                \
    PHTOP; PHMID(12); MFMA16(1, 1, a1f, b1f);                                   \
    __builtin_amdgcn_s_setprio(0); } while (0)

#define PH4QE(...) do { __VA_ARGS__;                                            \
    PHTOP; PHMID(0);  MFMA16(1, 1, a1f, b1f);                                   \
    __builtin_amdgcn_s_setprio(0); } while (0)

// EPI=0: C=bf16, val = acc * extra[row]; EPI=1: C=f32, val = acc + extra[col]
template <int EPI>
__global__ __launch_bounds__(512, 2) void gemm256(const ushort* __restrict__ A,
                                                  const ushort* __restrict__ B,
                                                  void* __restrict__ C,
                                                  const float* __restrict__ extra) {
    constexpr int K = 4096, N = 4096;
    __shared__ ushort sA[2][256 * 64];
    __shared__ ushort sB[2][256 * 64];

    const int tid  = threadIdx.x;
    const int w    = tid >> 6;
    const int lane = tid & 63;
    const int wm = w >> 2, wn = w & 3;

    // XCD-aware swizzle (nwg % 8 == 0 for both grids)
    const int nwg = gridDim.x;
    const int sw  = ((int)blockIdx.x & 7) * (nwg >> 3) + ((int)blockIdx.x >> 3);
    const int m0 = (sw >> 4) * 256;      // 16 tiles per N-row (N=4096)
    const int n0 = (sw & 15) * 256;

    const ushort* gA = A + (size_t)m0 * K;
    const ushort* gB = B + (size_t)n0 * K;

    // staging: dest = chunk*1024B + lane*16B (linear); global col pre-swizzled
    const int srow8 = lane >> 3;
    const int scol  = (((lane & 7) ^ (lane >> 3)) * 8);   // ushorts

    // fragment geometry (16x16x32: row=lane&15, k=(lane>>4)*8)
    const int fr   = lane & 15;
    const int fkb  = ((lane >> 4) & 3) * 16;          // byte offset along K
    const int swb  = (fr & 7) << 4;                   // read-side slot XOR
    const int arow = wm * 128 + fr;
    const int brow = wn * 64 + fr;

    f32x4 acc[8][4];
#pragma unroll
    for (int i = 0; i < 8; ++i)
#pragma unroll
        for (int j = 0; j < 4; ++j) acc[i][j] = (f32x4){0.f, 0.f, 0.f, 0.f};

    short8 a0f[2][4], a1f[2][4], b0f[2][2], b1f[2][2];

    // ---- prologue: stage t0 (AE,BE,BL,AL) + t1 (AE,BE,BL) = 14 loads ----
    STAGE2(gA, sA[0], 0, CH_AE); STAGE2(gB, sB[0], 0, CH_BE);
    STAGE2(gB, sB[0], 0, CH_BL); STAGE2(gA, sA[0], 0, CH_AL);
    STAGE2(gA, sA[1], 64, CH_AE); STAGE2(gB, sB[1], 64, CH_BE);
    STAGE2(gB, sB[1], 64, CH_BL);
    VM(8); ENDBAR;                                    // AE,BE,BL(0) resident
    READ_A(a0f, sA[0], 0); READ_B(b0f, sB[0], 0);     // "ph4(-1)" reads

    // ---- steady pairs: tiles 0..61 (stage refs <= tile 63) ----
    for (int pr = 0; pr < 31; ++pr) {
        const int t = 2 * pr;
        const int kb1 = (t + 1) * 64, kb2 = (t + 2) * 64, kb3 = (t + 3) * 64;
        // even tile t (cur = buf0)
        PH1Q(sB[0], STAGE2(gA, sA[1], kb1, CH_AL)); VM(8); ENDBAR;
        PH2Q(sA[0], STAGE2(gA, sA[0], kb2, CH_AE));        ENDBAR;
        PH3Q(       STAGE2(gB, sB[0], kb2, CH_BE)); VM(8); ENDBAR;
        PH4Q(sA[1], sB[1], STAGE2(gB, sB[0], kb2, CH_BL)); VM(8); ENDBAR;
        // odd tile t+1 (cur = buf1)
        PH1Q(sB[1], STAGE2(gA, sA[0], kb2, CH_AL)); VM(8); ENDBAR;
        PH2Q(sA[1], STAGE2(gA, sA[1], kb3, CH_AE));        ENDBAR;
        PH3Q(       STAGE2(gB, sB[1], kb3, CH_BE)); VM(8); ENDBAR;
        PH4Q(sA[0], sB[0], STAGE2(gB, sB[1], kb3, CH_BL)); VM(8); ENDBAR;
    }
    {   // ---- tail: tile 62 (buf0) ----
        PH1Q(sB[0], STAGE2(gA, sA[1], 63 * 64, CH_AL)); VM(8); ENDBAR;
        PH2Q(sA[0], ((void)0));                                ENDBAR;
        PH3Q(((void)0));                                VM(4); ENDBAR;
        PH4Q(sA[1], sB[1], ((void)0));                  VM(2); ENDBAR;
        // ---- tail: tile 63 (buf1) ----
        PH1Q(sB[1], ((void)0));                         VM(0); ENDBAR;
        PH2Q(sA[1], ((void)0));                                ENDBAR;
        PH3Q(((void)0));                                       ENDBAR;
        PH4QE(((void)0));
    }

    // ---- epilogue: C/D layout col=lane&15, row=(lane>>4)*4+reg ----
    const int rb = m0 + wm * 128 + ((lane >> 4) * 4);
    const int cb = n0 + wn * 64 + (lane & 15);
    if (EPI == 0) {
        ushort* Cw = (ushort*)C;
#pragma unroll
        for (int mi = 0; mi < 8; ++mi) {
#pragma unroll
            for (int r = 0; r < 4; ++r) {
                const int row = rb + mi * 16 + r;
                const float s = extra[row];
#pragma unroll
                for (int ni = 0; ni < 4; ++ni)
                    Cw[(size_t)row * N + cb + ni * 16] = f2bf(acc[mi][ni][r] * s);
            }
        }
    } else {
        float* Cf = (float*)C;
#pragma unroll
        for (int ni = 0; ni < 4; ++ni) {
            const float b = extra[cb + ni * 16];
#pragma unroll
            for (int mi = 0; mi < 8; ++mi) {
#pragma unroll
                for (int r = 0; r < 4; ++r) {
                    const int row = rb + mi * 16 + r;
                    Cf[(size_t)row * N + cb + ni * 16] = acc[mi][ni][r] + b;
                }
            }
        }
    }
}

// ---------- launch ----------
extern "C" void kernel_launch(void* const* d_in, const int* in_sizes, int n_in,
                              void* d_out, int out_size, void* d_ws, size_t ws_size,
                              hipStream_t stream) {
    const float* x     = (const float*)d_in[0];   // (4,2048,4096) f32
    const int*   widx  = (const int*)  d_in[1];   // (4096,4096) i32
    const float* wscal = (const float*)d_in[2];   // (4096,)
    const float* bias  = (const float*)d_in[3];   // (4096,)
    const float* rot   = (const float*)d_in[4];   // (4096,4096) f32
    const float* cb    = (const float*)d_in[5];   // (16,)
    float* out = (float*)d_out;                   // (4,2048,4096) f32

    constexpr size_t IN_F = 4096, OUT_F = 4096, MTOK = 8192;
    char* ws = (char*)d_ws;
    ushort* wq   = (ushort*)(ws);                 // 32 MiB: codebook[idx] bf16
    ushort* rbuf = (ushort*)(ws + 33554432);      // 32 MiB: rotation bf16
    ushort* xb   = (ushort*)(ws + 67108864);      // 64 MiB: x bf16
    ushort* wb   = (ushort*)(ws + 134217728);     // 32 MiB: dequantized W bf16
    (void)ws_size; (void)in_sizes; (void)n_in; (void)out_size;

    // converts (memory-bound)
    {
        int n4 = (int)(OUT_F * IN_F / 4);
        k_idx2bf<<<n4 / 256, 256, 0, stream>>>(widx, cb, wq, n4);
        k_f2bf<<<n4 / 256, 256, 0, stream>>>(rot, rbuf, n4);
        int n4x = (int)(MTOK * IN_F / 4);
        k_f2bf<<<n4x / 256, 256, 0, stream>>>(x, xb, n4x);
    }

    // GEMM A: W[o,j] = scale[o] * sum_i Wq[o,i] R[j,i]   (M=4096 -> 256 wgs)
    gemm256<0><<<dim3(256), 512, 0, stream>>>(wq, rbuf, (void*)wb, wscal);

    // GEMM B: out[m,o] = sum_j x[m,j] W[o,j] + bias[o]   (M=8192 -> 512 wgs)
    gemm256<1><<<dim3(512), 512, 0, stream>>>(xb, wb, (void*)out, bias);
}

// Round 8
// 662.676 us; speedup vs baseline: 2.6312x; 2.6312x over previous
//
#include <hip/hip_runtime.h>

// ---------- types ----------
typedef short short8 __attribute__((ext_vector_type(8)));   // 8 bf16 as i16
typedef float f32x4 __attribute__((ext_vector_type(4)));

#define GLOBAL_AS __attribute__((address_space(1)))
#define LDS_AS    __attribute__((address_space(3)))

__device__ __forceinline__ unsigned short f2bf(float f) {
    unsigned u = __builtin_bit_cast(unsigned, f);
    u += 0x7fffu + ((u >> 16) & 1u);          // round-to-nearest-even
    return (unsigned short)(u >> 16);
}

// ---------- convert kernels (memory-bound, vectorized) ----------
__global__ __launch_bounds__(256) void k_idx2bf(const int* __restrict__ idx,
                                                const float* __restrict__ cb,
                                                ushort* __restrict__ out, int n4) {
    int i = blockIdx.x * 256 + threadIdx.x;
    if (i >= n4) return;
    int4 v = reinterpret_cast<const int4*>(idx)[i];
    ushort4 o;
    o.x = f2bf(cb[v.x]); o.y = f2bf(cb[v.y]);
    o.z = f2bf(cb[v.z]); o.w = f2bf(cb[v.w]);
    reinterpret_cast<ushort4*>(out)[i] = o;
}

__global__ __launch_bounds__(256) void k_f2bf(const float* __restrict__ in,
                                              ushort* __restrict__ out, int n4) {
    int i = blockIdx.x * 256 + threadIdx.x;
    if (i >= n4) return;
    float4 v = reinterpret_cast<const float4*>(in)[i];
    ushort4 o;
    o.x = f2bf(v.x); o.y = f2bf(v.y); o.z = f2bf(v.z); o.w = f2bf(v.w);
    reinterpret_cast<ushort4*>(out)[i] = o;
}

// ---------- 256x256 bf16 gemm_bt (round-6 base + split-k2 + B0 preread) ----
// 512 thr = 8 waves (2M x 4N), per-wave 128x64, BK=64, 2 K-tile LDS dbuf.
// Per K-tile 4 quadrant phases. Reads/phase: 8(A0) / 4(B1) / 8(A1) / 4(B0
// of t+1, pre-read). Split-k2: lgkmcnt(4|2) -> 8 MFMA (k2=0) -> lgkmcnt(0)
// -> 8 MFMA (k2=1): second half of LDS service hides under first cluster.
// Stages (tile t): ph1 AL(t+1)->nx; ph2 AE(t+2), ph3 BE(t+2), ph4 BL(t+2)
// ->cur. Fences: vm(8) @ph3 end (completes AE,BE(t+1), enables ph4's B0
// pre-read), vm(6) @ph4 end (completes BL,AL(t+1)). In-flight ledger:
// 6 ->ph1 8 ->ph2 10 ->ph3 12 -vm8-> 8 ->ph4 10 -vm6-> 6 (invariant).
// Tails: tile 62 vm(4)@ph3, vm(0)@ph4; tile 63 no stage/fence/preread.
// Register budget (256 unified - 128 acc AGPR = 128 VGPR): operands
// aF 32 + b1f 16 + b0e 16 + b0o 16 = 80 + addressing ~30 -> fits.
// Swizzle (0 conflicts, r3-verified): linear LDS dest + pre-swizzled global
// col (slot s of row r holds s^(r&7)) + XOR'd ds_read address.

#define CH_AE(j) ((((j) & 8) << 1) | ((j) & 7))
#define CH_AL(j) (CH_AE(j) + 8)
#define CH_BE(j) ((((j) & 12) << 1) | ((j) & 3))
#define CH_BL(j) (CH_BE(j) + 4)

#define STAGE2(G, LDSBASE, KB, CF) do {                                         \
    const int c0_ = CF(2 * w);                                                  \
    const int c1_ = CF(2 * w + 1);                                              \
    __builtin_amdgcn_global_load_lds(                                           \
        (const GLOBAL_AS void*)((G) + (size_t)(c0_ * 8 + srow8) * 4096 + (KB) + scol), \
        (LDS_AS void*)((LDSBASE) + c0_ * 512), 16, 0, 0);                       \
    __builtin_amdgcn_global_load_lds(                                           \
        (const GLOBAL_AS void*)((G) + (size_t)(c1_ * 8 + srow8) * 4096 + (KB) + scol), \
        (LDS_AS void*)((LDSBASE) + c1_ * 512), 16, 0, 0);                       \
} while (0)

// k2-major issue order (k2 outer) so lgkmcnt(N) leaves exactly k2=1 in flight
#define READ_A(DST, BASE, MH) do {                                              \
    _Pragma("unroll")                                                           \
    for (int k2 = 0; k2 < 2; ++k2)                                              \
        _Pragma("unroll")                                                       \
        for (int mi = 0; mi < 4; ++mi) {                                        \
            const int lb = (arow + (MH) * 64 + mi * 16) * 128 + k2 * 64 + fkb;  \
            DST[k2][mi] = *reinterpret_cast<const short8*>((const char*)(BASE) + (lb ^ swb)); \
        }                                                                       \
} while (0)

#define READ_B(DST, BASE, NH) do {                                              \
    _Pragma("unroll")                                                           \
    for (int k2 = 0; k2 < 2; ++k2)                                              \
        _Pragma("unroll")                                                       \
        for (int ni = 0; ni < 2; ++ni) {                                        \
            const int lb = (brow + (NH) * 32 + ni * 16) * 128 + k2 * 64 + fkb;  \
            DST[k2][ni] = *reinterpret_cast<const short8*>((const char*)(BASE) + (lb ^ swb)); \
        }                                                                       \
} while (0)

#define MFMA8(MH, NH, K2, AF, BF)                                               \
    _Pragma("unroll")                                                           \
    for (int mi = 0; mi < 4; ++mi)                                              \
        _Pragma("unroll")                                                       \
        for (int ni = 0; ni < 2; ++ni)                                          \
            acc[(MH) * 4 + mi][(NH) * 2 + ni] =                                 \
                __builtin_amdgcn_mfma_f32_16x16x32_bf16(                        \
                    AF[K2][mi], BF[K2][ni], acc[(MH) * 4 + mi][(NH) * 2 + ni], 0, 0, 0)

#define VM(N) asm volatile("s_waitcnt vmcnt(" #N ")" ::: "memory")

#define LGS(N) do {                                                             \
    asm volatile("s_waitcnt lgkmcnt(" #N ")" ::: "memory");                     \
    __builtin_amdgcn_sched_barrier(0);                                          \
} while (0)

#define ENDBAR do {                                                             \
    asm volatile("" ::: "memory");                                              \
    __builtin_amdgcn_s_barrier();                                               \
    asm volatile("" ::: "memory");                                              \
} while (0)

#define PHTOP do {                                                              \
    asm volatile("" ::: "memory");                                              \
    __builtin_amdgcn_s_barrier();                                               \
} while (0)

// phase cores (call sites append optional VM fence + ENDBAR)
#define PH1c(At, B0S, ...) do { READ_A(aF, At, 0); __VA_ARGS__; PHTOP; LGS(4);  \
    __builtin_amdgcn_s_setprio(1); MFMA8(0, 0, 0, aF, B0S); LGS(0);             \
    MFMA8(0, 0, 1, aF, B0S); __builtin_amdgcn_s_setprio(0); } while (0)

#define PH2c(Bt, ...) do { READ_B(b1f, Bt, 1); __VA_ARGS__; PHTOP; LGS(2);      \
    __builtin_amdgcn_s_setprio(1); MFMA8(0, 1, 0, aF, b1f); LGS(0);             \
    MFMA8(0, 1, 1, aF, b1f); __builtin_amdgcn_s_setprio(0); } while (0)

#define PH3c(At, B0S, ...) do { READ_A(aF, At, 1); __VA_ARGS__; PHTOP; LGS(4);  \
    __builtin_amdgcn_s_setprio(1); MFMA8(1, 0, 0, aF, B0S); LGS(0);             \
    MFMA8(1, 0, 1, aF, B0S); __builtin_amdgcn_s_setprio(0); } while (0)

// ph4: MFMA operands (aF=A1, b1f) already drained; B0(t+1) pre-read rides
// through (no lgkm wait here; next ph1's LGS(4) completes it)
#define PH4c(B0D, Bn, ...) do { READ_B(B0D, Bn, 0); __VA_ARGS__; PHTOP;         \
    __builtin_amdgcn_s_setprio(1); MFMA8(1, 1, 0, aF, b1f);                     \
    MFMA8(1, 1, 1, aF, b1f); __builtin_amdgcn_s_setprio(0); } while (0)

#define PH4e(...) do { __VA_ARGS__; PHTOP;                                      \
    __builtin_amdgcn_s_setprio(1); MFMA8(1, 1, 0, aF, b1f);                     \
    MFMA8(1, 1, 1, aF, b1f); __builtin_amdgcn_s_setprio(0); } while (0)

// EPI=0: C=bf16, val = acc * extra[row]; EPI=1: C=f32, val = acc + extra[col]
template <int EPI>
__global__ __launch_bounds__(512, 2) void gemm256(const ushort* __restrict__ A,
                                                  const ushort* __restrict__ B,
                                                  void* __restrict__ C,
                                                  const float* __restrict__ extra) {
    constexpr int K = 4096, N = 4096;
    __shared__ ushort sA[2][256 * 64];
    __shared__ ushort sB[2][256 * 64];

    const int tid  = threadIdx.x;
    const int w    = tid >> 6;
    const int lane = tid & 63;
    const int wm = w >> 2, wn = w & 3;

    // XCD-aware swizzle (nwg % 8 == 0 for both grids)
    const int nwg = gridDim.x;
    const int sw  = ((int)blockIdx.x & 7) * (nwg >> 3) + ((int)blockIdx.x >> 3);
    const int m0 = (sw >> 4) * 256;      // 16 tiles per N-row (N=4096)
    const int n0 = (sw & 15) * 256;

    const ushort* gA = A + (size_t)m0 * K;
    const ushort* gB = B + (size_t)n0 * K;

    // staging: dest = chunk*1024B + lane*16B (linear); global col pre-swizzled
    const int srow8 = lane >> 3;
    const int scol  = (((lane & 7) ^ (lane >> 3)) * 8);   // ushorts

    // fragment geometry (16x16x32: row=lane&15, k=(lane>>4)*8)
    const int fr   = lane & 15;
    const int fkb  = ((lane >> 4) & 3) * 16;          // byte offset along K
    const int swb  = (fr & 7) << 4;                   // read-side slot XOR
    const int arow = wm * 128 + fr;
    const int brow = wn * 64 + fr;

    f32x4 acc[8][4];
#pragma unroll
    for (int i = 0; i < 8; ++i)
#pragma unroll
        for (int j = 0; j < 4; ++j) acc[i][j] = (f32x4){0.f, 0.f, 0.f, 0.f};

    short8 aF[2][4], b1f[2][2], b0e[2][2], b0o[2][2];

    // ---- prologue: stage t0 (AE,BE,BL,AL) + t1 (AE,BE,BL) = 14 loads ----
    STAGE2(gA, sA[0], 0, CH_AE); STAGE2(gB, sB[0], 0, CH_BE);
    STAGE2(gB, sB[0], 0, CH_BL); STAGE2(gA, sA[0], 0, CH_AL);
    STAGE2(gA, sA[1], 64, CH_AE); STAGE2(gB, sB[1], 64, CH_BE);
    STAGE2(gB, sB[1], 64, CH_BL);
    VM(6); ENDBAR;                                    // tile0 fully resident
    READ_B(b0e, sB[0], 0);                            // pre-read B0(0)

    // ---- steady pairs: tiles 0..61 ----
    for (int pr = 0; pr < 31; ++pr) {
        const int t = 2 * pr;
        const int kb1 = (t + 1) * 64, kb2 = (t + 2) * 64, kb3 = (t + 3) * 64;
        // even tile t (cur=buf0): uses b0e; ph4 pre-reads B0(t+1) -> b0o
        PH1c(sA[0], b0e, STAGE2(gA, sA[1], kb1, CH_AL));        ENDBAR;
        PH2c(sB[0],      STAGE2(gA, sA[0], kb2, CH_AE));        ENDBAR;
        PH3c(sA[0], b0e, STAGE2(gB, sB[0], kb2, CH_BE)); VM(8); ENDBAR;
        PH4c(b0o, sB[1], STAGE2(gB, sB[0], kb2, CH_BL)); VM(6); ENDBAR;
        // odd tile t+1 (cur=buf1): uses b0o; ph4 pre-reads B0(t+2) -> b0e
        PH1c(sA[1], b0o, STAGE2(gA, sA[0], kb2, CH_AL));        ENDBAR;
        PH2c(sB[1],      STAGE2(gA, sA[1], kb3, CH_AE));        ENDBAR;
        PH3c(sA[1], b0o, STAGE2(gB, sB[1], kb3, CH_BE)); VM(8); ENDBAR;
        PH4c(b0e, sB[0], STAGE2(gB, sB[1], kb3, CH_BL)); VM(6); ENDBAR;
    }
    {   // ---- tail: tile 62 (even, buf0) ----
        PH1c(sA[0], b0e, STAGE2(gA, sA[1], 63 * 64, CH_AL));    ENDBAR;
        PH2c(sB[0], ((void)0));                                 ENDBAR;
        PH3c(sA[0], b0e, ((void)0));                     VM(4); ENDBAR;
        PH4c(b0o, sB[1], ((void)0));                     VM(0); ENDBAR;
        // ---- tail: tile 63 (odd, buf1) ----
        PH1c(sA[1], b0o, ((void)0));                            ENDBAR;
        PH2c(sB[1], ((void)0));                                 ENDBAR;
        PH3c(sA[1], b0o, ((void)0));                            ENDBAR;
        PH4e(((void)0));
    }

    // ---- epilogue: C/D layout col=lane&15, row=(lane>>4)*4+reg ----
    const int rb = m0 + wm * 128 + ((lane >> 4) * 4);
    const int cb = n0 + wn * 64 + (lane & 15);
    if (EPI == 0) {
        ushort* Cw = (ushort*)C;
#pragma unroll
        for (int mi = 0; mi < 8; ++mi) {
#pragma unroll
            for (int r = 0; r < 4; ++r) {
                const int row = rb + mi * 16 + r;
                const float s = extra[row];
#pragma unroll
                for (int ni = 0; ni < 4; ++ni)
                    Cw[(size_t)row * N + cb + ni * 16] = f2bf(acc[mi][ni][r] * s);
            }
        }
    } else {
        float* Cf = (float*)C;
#pragma unroll
        for (int ni = 0; ni < 4; ++ni) {
            const float b = extra[cb + ni * 16];
#pragma unroll
            for (int mi = 0; mi < 8; ++mi) {
#pragma unroll
                for (int r = 0; r < 4; ++r) {
                    const int row = rb + mi * 16 + r;
                    Cf[(size_t)row * N + cb + ni * 16] = acc[mi][ni][r] + b;
                }
            }
        }
    }
}

// ---------- launch ----------
extern "C" void kernel_launch(void* const* d_in, const int* in_sizes, int n_in,
                              void* d_out, int out_size, void* d_ws, size_t ws_size,
                              hipStream_t stream) {
    const float* x     = (const float*)d_in[0];   // (4,2048,4096) f32
    const int*   widx  = (const int*)  d_in[1];   // (4096,4096) i32
    const float* wscal = (const float*)d_in[2];   // (4096,)
    const float* bias  = (const float*)d_in[3];   // (4096,)
    const float* rot   = (const float*)d_in[4];   // (4096,4096) f32
    const float* cb    = (const float*)d_in[5];   // (16,)
    float* out = (float*)d_out;                   // (4,2048,4096) f32

    constexpr size_t IN_F = 4096, OUT_F = 4096, MTOK = 8192;
    char* ws = (char*)d_ws;
    ushort* wq   = (ushort*)(ws);                 // 32 MiB: codebook[idx] bf16
    ushort* rbuf = (ushort*)(ws + 33554432);      // 32 MiB: rotation bf16
    ushort* xb   = (ushort*)(ws + 67108864);      // 64 MiB: x bf16
    ushort* wb   = (ushort*)(ws + 134217728);     // 32 MiB: dequantized W bf16
    (void)ws_size; (void)in_sizes; (void)n_in; (void)out_size;

    // converts (memory-bound)
    {
        int n4 = (int)(OUT_F * IN_F / 4);
        k_idx2bf<<<n4 / 256, 256, 0, stream>>>(widx, cb, wq, n4);
        k_f2bf<<<n4 / 256, 256, 0, stream>>>(rot, rbuf, n4);
        int n4x = (int)(MTOK * IN_F / 4);
        k_f2bf<<<n4x / 256, 256, 0, stream>>>(x, xb, n4x);
    }

    // GEMM A: W[o,j] = scale[o] * sum_i Wq[o,i] R[j,i]   (M=4096 -> 256 wgs)
    gemm256<0><<<dim3(256), 512, 0, stream>>>(wq, rbuf, (void*)wb, wscal);

    // GEMM B: out[m,o] = sum_j x[m,j] W[o,j] + bias[o]   (M=8192 -> 512 wgs)
    gemm256<1><<<dim3(512), 512, 0, stream>>>(xb, wb, (void*)out, bias);
}